// Round 1
// baseline (283.507 us; speedup 1.0000x reference)
//
#include <hip/hip_runtime.h>
#include <stdint.h>

// ---------------------------------------------------------------------------
// PRNG mode:
//  0 = threefry_partitionable (JAX >= 0.5 default): bits[i] = lo-word of
//      threefry2x32(key, (hi32(i)=0, lo32(i)=i))  (u64 combine truncated)
//  1 = partitionable but hi-word (o0) variant
//  2 = original split-iota: bits[i<H] = o0 of (i, i+H); bits[i>=H] = o1 of
//      (i-H, i), H = total/2 = 320000
// ---------------------------------------------------------------------------
#define PRNG_MODE 0

#define BB 64
#define NC 1000       // customers per instance
#define KC 10         // clusters
#define TOTAL_BITS (BB * NC * KC)   // 640000
#define HALF_BITS (TOTAL_BITS / 2)  // 320000

__host__ __device__ inline void threefry2x32(uint32_t k0, uint32_t k1,
                                             uint32_t x0, uint32_t x1,
                                             uint32_t* o0, uint32_t* o1) {
  uint32_t k2 = k0 ^ k1 ^ 0x1BD11BDAu;
  x0 += k0; x1 += k1;
#define TF_R(R) { x0 += x1; x1 = (x1 << (R)) | (x1 >> (32 - (R))); x1 ^= x0; }
  TF_R(13) TF_R(15) TF_R(26) TF_R(6)
  x0 += k1; x1 += k2 + 1u;
  TF_R(17) TF_R(29) TF_R(16) TF_R(24)
  x0 += k2; x1 += k0 + 2u;
  TF_R(13) TF_R(15) TF_R(26) TF_R(6)
  x0 += k0; x1 += k1 + 3u;
  TF_R(17) TF_R(29) TF_R(16) TF_R(24)
  x0 += k1; x1 += k2 + 4u;
  TF_R(13) TF_R(15) TF_R(26) TF_R(6)
  x0 += k2; x1 += k0 + 5u;
#undef TF_R
  *o0 = x0; *o1 = x1;
}

__device__ inline uint32_t rand_bits(uint32_t ks0, uint32_t ks1, uint32_t p) {
#if PRNG_MODE == 0
  uint32_t a, b; threefry2x32(ks0, ks1, 0u, p, &a, &b); return b;
#elif PRNG_MODE == 1
  uint32_t a, b; threefry2x32(ks0, ks1, 0u, p, &a, &b); return a;
#else
  uint32_t a, b;
  if (p < HALF_BITS) { threefry2x32(ks0, ks1, p, p + HALF_BITS, &a, &b); return a; }
  else               { threefry2x32(ks0, ks1, p - HALF_BITS, p, &a, &b); return b; }
#endif
}

// ---------------------------------------------------------------------------
// Kernel 1: categorical sampling (gumbel argmax) + per-instance logprob sum
// ---------------------------------------------------------------------------
__global__ __launch_bounds__(256) void k_sample(
    const float* __restrict__ logits,   // (64,1001,10)
    uint32_t ks0, uint32_t ks1,
    uint8_t* __restrict__ assign,       // (64,1000)
    double* __restrict__ lp) {          // (64,)
  int b = blockIdx.x;
  int tid = threadIdx.x;
  const float TINY = 1.1754943508222875e-38f;
  double acc = 0.0;
  for (int n = tid; n < NC; n += 256) {
    const float* lrow = logits + ((size_t)b * 1001 + (size_t)(n + 1)) * KC;
    float xs[KC];
#pragma unroll
    for (int k = 0; k < KC; ++k) xs[k] = lrow[k];
    uint32_t pbase = (uint32_t)(b * NC + n) * (uint32_t)KC;
    int best_k = 0;
    float best_v = -INFINITY;
    float xmax = -INFINITY;
#pragma unroll
    for (int k = 0; k < KC; ++k) {
      uint32_t bits = rand_bits(ks0, ks1, pbase + (uint32_t)k);
      float f = __uint_as_float((bits >> 9) | 0x3f800000u) - 1.0f;   // [0,1)
      float u = (f > 0.0f) ? f : TINY;   // JAX: floats*(1-tiny)+tiny, max(tiny,·)
      float g = -logf(-logf(u));         // gumbel
      float v = g + xs[k];
      if (v > best_v) { best_v = v; best_k = k; }   // first-index tie-break
      xmax = fmaxf(xmax, xs[k]);
    }
    float s = 0.0f;
#pragma unroll
    for (int k = 0; k < KC; ++k) s += expf(xs[k] - xmax);
    float slp = (xs[best_k] - xmax) - logf(s);      // log_softmax at sample
    acc += (double)slp;
    assign[b * NC + n] = (uint8_t)best_k;
  }
  __shared__ double red[256];
  red[tid] = acc;
  __syncthreads();
  for (int off = 128; off > 0; off >>= 1) {
    if (tid < off) red[tid] += red[tid + off];
    __syncthreads();
  }
  if (tid == 0) lp[b] = red[0];
}

// ---------------------------------------------------------------------------
// Kernel 2: capacity split (per-cluster scan) + per-route NN routing distance
// ---------------------------------------------------------------------------
__global__ __launch_bounds__(256) void k_route(
    const float* __restrict__ coords,    // (64,1001,2)
    const float* __restrict__ demands,   // (64,1001)
    const float* __restrict__ capacity,  // (64,)
    const uint8_t* __restrict__ assign,  // (64,1000)
    double* __restrict__ dist) {         // (64,)
  int b = blockIdx.x;
  int tid = threadIdx.x;

  __shared__ float sx[NC], sy[NC], sdem[NC];
  __shared__ uint8_t sa[NC];
  __shared__ uint16_t mem[NC];     // customer local idx, grouped cluster->route
  __shared__ uint16_t rs[NC];      // route start in mem
  __shared__ uint16_t rl[NC];      // route length
  __shared__ uint8_t vis[NC];
  __shared__ int mc[KC], rc[KC], mbase[KC], rbase[KC];
  __shared__ int nroutes;
  __shared__ float sdepot[2];
  __shared__ double red[256];

  const float* cb = coords + (size_t)b * 1001 * 2;
  if (tid == 0) { sdepot[0] = cb[0]; sdepot[1] = cb[1]; }
  for (int i = tid; i < NC; i += 256) {
    sx[i]   = cb[(i + 1) * 2 + 0];
    sy[i]   = cb[(i + 1) * 2 + 1];
    sdem[i] = demands[(size_t)b * 1001 + (size_t)(i + 1)];
    sa[i]   = assign[b * NC + i];
    vis[i]  = 0;
  }
  __syncthreads();
  float cap = capacity[b];

  // walk 1: per-cluster member & route counts (exact f32 scan semantics)
  if (tid < KC) {
    int k = tid, m = 0, r = 0;
    float load = 0.0f; bool nonempty = false;
    for (int i = 0; i < NC; ++i) {
      if (sa[i] == (uint8_t)k) {
        float d = sdem[i];
        if (nonempty && (load + d > cap)) { r++; load = d; }
        else load += d;
        nonempty = true;
        m++;
      }
    }
    mc[k] = m;
    rc[k] = nonempty ? (r + 1) : 0;
  }
  __syncthreads();
  if (tid == 0) {
    int ms = 0, rsum = 0;
    for (int k = 0; k < KC; ++k) {
      mbase[k] = ms; rbase[k] = rsum;
      ms += mc[k]; rsum += rc[k];
    }
    nroutes = rsum;
  }
  __syncthreads();

  // walk 2: place members (index order) + route boundaries
  if (tid < KC) {
    int k = tid;
    int mp = mbase[k], rp = rbase[k], cur = mp;
    float load = 0.0f; bool nonempty = false;
    for (int i = 0; i < NC; ++i) {
      if (sa[i] == (uint8_t)k) {
        float d = sdem[i];
        if (nonempty && (load + d > cap)) {
          rs[rp] = (uint16_t)cur; rl[rp] = (uint16_t)(mp - cur); rp++;
          cur = mp; load = d;
        } else load += d;
        nonempty = true;
        mem[mp++] = (uint16_t)i;
      }
    }
    if (nonempty) { rs[rp] = (uint16_t)cur; rl[rp] = (uint16_t)(mp - cur); }
  }
  __syncthreads();

  // NN tour per route (disjoint mem/vis slices -> no races)
  double acc = 0.0;
  float dx0 = sdepot[0], dy0 = sdepot[1];
  int NR = nroutes;
  for (int r = tid; r < NR; r += 256) {
    int s = rs[r], L = rl[r];
    float px = dx0, py = dy0, racc = 0.0f;
    for (int step = 0; step < L; ++step) {
      float best = INFINITY; int bj = -1;
      for (int j = s; j < s + L; ++j) {
        if (!vis[j]) {
          int i = mem[j];
          float ddx = sx[i] - px, ddy = sy[i] - py;
          float d = sqrtf(ddx * ddx + ddy * ddy);
          if (d < best) { best = d; bj = j; }   // min idx on ties
        }
      }
      vis[bj] = 1;
      int i = mem[bj];
      px = sx[i]; py = sy[i];
      racc += best;                              // f32, scan order
    }
    float ddx = px - dx0, ddy = py - dy0;
    racc += sqrtf(ddx * ddx + ddy * ddy);        // return-to-depot leg
    acc += (double)racc;
  }
  red[tid] = acc;
  __syncthreads();
  for (int off = 128; off > 0; off >>= 1) {
    if (tid < off) red[tid] += red[tid + off];
    __syncthreads();
  }
  if (tid == 0) dist[b] = red[0];
}

// ---------------------------------------------------------------------------
// Kernel 3: baseline + REINFORCE loss
// ---------------------------------------------------------------------------
__global__ void k_final(const double* __restrict__ lp,
                        const double* __restrict__ dist,
                        float* __restrict__ out) {
  if (threadIdx.x == 0 && blockIdx.x == 0) {
    float df[BB], lf[BB];
    double sum = 0.0;
    for (int i = 0; i < BB; ++i) {
      df[i] = (float)dist[i];
      lf[i] = (float)lp[i];
      sum += (double)df[i];
    }
    double mean = sum / (double)BB;
    float meanf = (float)mean;
    double loss = 0.0;
    for (int i = 0; i < BB; ++i)
      loss += ((double)df[i] - (double)meanf) * (double)lf[i];
    loss /= (double)BB;
    out[0] = (float)loss;
    out[1] = (float)mean;
  }
}

extern "C" void kernel_launch(void* const* d_in, const int* in_sizes, int n_in,
                              void* d_out, int out_size, void* d_ws, size_t ws_size,
                              hipStream_t stream) {
  const float* logits   = (const float*)d_in[0];  // (64,1001,10)
  const float* coords   = (const float*)d_in[1];  // (64,1001,2)
  const float* demands  = (const float*)d_in[2];  // (64,1001)
  const float* capacity = (const float*)d_in[3];  // (64,)
  // d_in[4] = n_samples (fixed 1 for this problem instance)

  uint8_t* ws   = (uint8_t*)d_ws;
  uint8_t* assign = ws;                                  // 64000 B
  double* lp    = (double*)(ws + 64 * 1024);             // 512 B
  double* dist  = (double*)(ws + 64 * 1024 + 1024);      // 512 B

  // ks = fold_in(key(42), 0) = threefry2x32(k=(0,42), ctr=(0,0))
  uint32_t ks0, ks1;
  threefry2x32(0u, 42u, 0u, 0u, &ks0, &ks1);

  k_sample<<<dim3(BB), dim3(256), 0, stream>>>(logits, ks0, ks1, assign, lp);
  k_route<<<dim3(BB), dim3(256), 0, stream>>>(coords, demands, capacity, assign, dist);
  k_final<<<dim3(1), dim3(64), 0, stream>>>(lp, dist, (float*)d_out);
}